// Round 6
// baseline (253.785 us; speedup 1.0000x reference)
//
#include <hip/hip_runtime.h>
#include <hip/hip_fp16.h>

#define N_NODES 50000
#define N_EDGES 800000
#define D_FEAT 128
#define HEADS 8
#define UNITS 32
#define HU (HEADS * UNITS) /* 256 */
#define LEAKY 0.2f
#define EPSV 1e-7f
#define NBLK 196 /* ceil(50000/256) */

typedef _Float16 half8 __attribute__((ext_vector_type(8)));
typedef float f32x4 __attribute__((ext_vector_type(4)));

struct h4pk { __half2 a, b; }; // 4 fp16 channels = 8 bytes

// ---- fused: x fp32->fp16 | W -> W^T fp16 | in-degree counts ----
#define XBLK 3125             /* 3125*256*8 = 6,400,000 = N_NODES*D_FEAT */
#define WBLK 128              /* 128*256 = 32768 = D_FEAT*HU */
#define EBLK 3125             /* 3125*256 = 800,000 = N_EDGES */
__global__ __launch_bounds__(256) void k_conv(const float* __restrict__ x,
                                              const float* __restrict__ W,
                                              const int* __restrict__ edges,
                                              __half* __restrict__ x16,
                                              __half* __restrict__ Wt,
                                              int* __restrict__ counts) {
    const int b = blockIdx.x, t = threadIdx.x;
    if (b < XBLK) {
        const int i = (b * 256 + t) * 8;
        const float4 v0 = *reinterpret_cast<const float4*>(x + i);
        const float4 v1 = *reinterpret_cast<const float4*>(x + i + 4);
        half8 o;
        o[0] = (_Float16)v0.x; o[1] = (_Float16)v0.y;
        o[2] = (_Float16)v0.z; o[3] = (_Float16)v0.w;
        o[4] = (_Float16)v1.x; o[5] = (_Float16)v1.y;
        o[6] = (_Float16)v1.z; o[7] = (_Float16)v1.w;
        *reinterpret_cast<half8*>(x16 + i) = o;
    } else if (b < XBLK + WBLK) {
        const int i = (b - XBLK) * 256 + t;   // i = n*128 + k
        const int n = i >> 7, k = i & 127;
        Wt[i] = __float2half(W[k * HU + n]);  // Wt[n][k] = W[k][n]
    } else {
        const int e = (b - XBLK - WBLK) * 256 + t;
        if (e < N_EDGES) atomicAdd(&counts[edges[2 * e + 1]], 1);
    }
}

// ---- MFMA GEMM: h(fp16) = x16 @ Wt^T, fused f = sum(h*ka1, units) ----
__global__ __launch_bounds__(64) void k_gemm(const __half* __restrict__ x16,
                                             const __half* __restrict__ Wt,
                                             const float* __restrict__ ka1,
                                             __half* __restrict__ h,
                                             float* __restrict__ f) {
    __shared__ __align__(16) __half hs[16 * HU]; // 8 KB
    const int l = threadIdx.x;
    const int row16 = l & 15, kg = l >> 4;
    const size_t rbase = (size_t)blockIdx.x * 16;

    half8 a[4];
#pragma unroll
    for (int ks = 0; ks < 4; ++ks)
        a[ks] = *reinterpret_cast<const half8*>(x16 + (rbase + row16) * D_FEAT + ks * 32 + kg * 8);

    f32x4 acc[16];
#pragma unroll
    for (int ct = 0; ct < 16; ++ct) acc[ct] = (f32x4){0.f, 0.f, 0.f, 0.f};

#pragma unroll
    for (int ct = 0; ct < 16; ++ct) {
        const __half* wp = Wt + (ct * 16 + row16) * D_FEAT + kg * 8;
#pragma unroll
        for (int ks = 0; ks < 4; ++ks) {
            const half8 bf = *reinterpret_cast<const half8*>(wp + ks * 32);
            acc[ct] = __builtin_amdgcn_mfma_f32_16x16x32_f16(a[ks], bf, acc[ct], 0, 0, 0);
        }
    }

#pragma unroll
    for (int ct = 0; ct < 16; ++ct) {
        const int col = ct * 16 + row16;
#pragma unroll
        for (int r = 0; r < 4; ++r)
            hs[(kg * 4 + r) * HU + col] = __float2half(acc[ct][r]);
    }
    __syncthreads();

#pragma unroll
    for (int j = 0; j < 8; ++j) {
        const int slot = j * 64 + l;
        const half8 v = *reinterpret_cast<const half8*>(hs + slot * 8);
        *reinterpret_cast<half8*>(h + rbase * HU + slot * 8) = v;
    }

#pragma unroll
    for (int hf = 0; hf < 2; ++hf) {
        const int o = hf * 64 + l;
        const int row = o >> 3, hd = o & 7;
        const __half* hp = hs + row * HU + hd * UNITS;
        const float* kp = ka1 + hd * UNITS;
        float s = 0.f;
#pragma unroll
        for (int u = 0; u < UNITS; u += 8) {
            const half8 hv = *reinterpret_cast<const half8*>(hp + u);
            const float4 k0 = *reinterpret_cast<const float4*>(kp + u);
            const float4 k1 = *reinterpret_cast<const float4*>(kp + u + 4);
            s += (float)hv[0] * k0.x + (float)hv[1] * k0.y + (float)hv[2] * k0.z + (float)hv[3] * k0.w;
            s += (float)hv[4] * k1.x + (float)hv[5] * k1.y + (float)hv[6] * k1.z + (float)hv[7] * k1.w;
        }
        f[rbase * HEADS + o] = s;
    }
}

// ---- hierarchical scan ----
__global__ __launch_bounds__(256) void k_scanA(const int* __restrict__ counts,
                                               int* __restrict__ partials) {
    const int i = blockIdx.x * 256 + threadIdx.x;
    int v = (i < N_NODES) ? counts[i] : 0;
#pragma unroll
    for (int m = 32; m >= 1; m >>= 1) v += __shfl_xor(v, m);
    __shared__ int ws[4];
    if ((threadIdx.x & 63) == 0) ws[threadIdx.x >> 6] = v;
    __syncthreads();
    if (threadIdx.x == 0) partials[blockIdx.x] = ws[0] + ws[1] + ws[2] + ws[3];
}

__global__ __launch_bounds__(256) void k_scanB(int* __restrict__ partials) {
    __shared__ int s[256];
    const int t = threadIdx.x;
    const int v = (t < NBLK) ? partials[t] : 0;
    s[t] = v;
    __syncthreads();
    for (int o = 1; o < 256; o <<= 1) {
        const int u = (t >= o) ? s[t - o] : 0;
        __syncthreads();
        s[t] += u;
        __syncthreads();
    }
    if (t < NBLK) partials[t] = s[t] - v; // exclusive
}

__global__ __launch_bounds__(256) void k_scanC(const int* __restrict__ counts,
                                               const int* __restrict__ partials,
                                               int* __restrict__ offs) {
    __shared__ int s[256];
    const int t = threadIdx.x;
    const int i = blockIdx.x * 256 + t;
    const int v = (i < N_NODES) ? counts[i] : 0;
    s[t] = v;
    __syncthreads();
    for (int o = 1; o < 256; o <<= 1) {
        const int u = (t >= o) ? s[t - o] : 0;
        __syncthreads();
        s[t] += u;
        __syncthreads();
    }
    if (i < N_NODES) offs[i] = partials[blockIdx.x] + s[t] - v; // exclusive
}

// ---- fused: g[v]=f[targets[v]] + CSR fill (offs becomes segment END) ----
__global__ __launch_bounds__(256) void k_fillg(const int* __restrict__ edges,
                                               const float* __restrict__ f,
                                               float* __restrict__ g,
                                               int* __restrict__ offs,
                                               int* __restrict__ elist) {
    const int i = blockIdx.x * 256 + threadIdx.x;
    if (i < N_NODES) {
        const int t2 = edges[2 * i + 1];
        const float4 A = *reinterpret_cast<const float4*>(f + (size_t)t2 * HEADS);
        const float4 B = *reinterpret_cast<const float4*>(f + (size_t)t2 * HEADS + 4);
        *reinterpret_cast<float4*>(g + (size_t)i * HEADS) = A;
        *reinterpret_cast<float4*>(g + (size_t)i * HEADS + 4) = B;
    }
    if (i < N_EDGES) {
        const int s = edges[2 * i];
        const int t = edges[2 * i + 1];
        const int p = atomicAdd(&offs[t], 1);
        elist[p] = s;
    }
}

// ---- per-node softmax: precompute fp16 weights (CSR order) + 1/denom ----
// 4 nodes per block; per node: 64 lanes = 8 edges x 8 heads.
__global__ __launch_bounds__(256) void k_max(const int* __restrict__ elist,
                                             const float* __restrict__ f,
                                             const float* __restrict__ g,
                                             const int* __restrict__ offs, // segment END
                                             const int* __restrict__ counts,
                                             __half* __restrict__ wlist,
                                             float* __restrict__ invd) {
    const int n = blockIdx.x * 4 + (threadIdx.x >> 6);
    if (n >= N_NODES) return;
    const int lane = threadIdx.x & 63;
    const int eo = lane >> 3, hd = lane & 7;
    const int end = offs[n];
    const int start = end - counts[n];
    const float fn = f[(size_t)n * HEADS + hd];

    // sweep 1: per-head max (lane-parallel over edges)
    float mx = -INFINITY;
    for (int p = start + eo; p < end; p += 8) {
        const int s = elist[p];
        float z = fn + g[(size_t)s * HEADS + hd];
        z = (z > 0.f) ? z : LEAKY * z;
        mx = fmaxf(mx, z);
    }
    mx = fmaxf(mx, __shfl_xor(mx, 8));
    mx = fmaxf(mx, __shfl_xor(mx, 16));
    mx = fmaxf(mx, __shfl_xor(mx, 32));

    // sweep 2: weights (fp16, CSR-ordered coalesced) + denom
    float d = 0.f;
    for (int p = start + eo; p < end; p += 8) {
        const int s = elist[p];
        float z = fn + g[(size_t)s * HEADS + hd];
        z = (z > 0.f) ? z : LEAKY * z;
        const __half wh = __float2half(__expf(z - mx));
        wlist[(size_t)p * HEADS + hd] = wh;
        d += __half2float(wh);
    }
    d += __shfl_xor(d, 8);
    d += __shfl_xor(d, 16);
    d += __shfl_xor(d, 32);
    if (eo == 0) invd[(size_t)n * HEADS + hd] = 1.f / (d + EPSV);
}

// ---- pure weighted gather: acc += w[p] * h[src], then scale + bias + ELU ----
__global__ __launch_bounds__(256) void k_out(const __half* __restrict__ h,
                                             const int* __restrict__ elist,
                                             const __half* __restrict__ wlist,
                                             const float* __restrict__ invd,
                                             const int* __restrict__ offs, // segment END
                                             const int* __restrict__ counts,
                                             const float* __restrict__ bias,
                                             float* __restrict__ out) {
    const int n = blockIdx.x * 4 + (threadIdx.x >> 6);
    if (n >= N_NODES) return;
    const int lane = threadIdx.x & 63;
    const int head = lane >> 3;
    const int c4 = lane * 4;
    const int end = offs[n];
    const int start = end - counts[n];

    float4 acc = make_float4(0.f, 0.f, 0.f, 0.f);
#pragma unroll 2
    for (int p = start; p < end; ++p) {
        const int s = elist[p];
        const float w = __half2float(wlist[(size_t)p * HEADS + head]);
        const h4pk hv = *reinterpret_cast<const h4pk*>(h + (size_t)s * HU + c4);
        const float2 fa = __half22float2(hv.a);
        const float2 fb = __half22float2(hv.b);
        acc.x += w * fa.x;
        acc.y += w * fa.y;
        acc.z += w * fb.x;
        acc.w += w * fb.y;
    }

    const float iv = invd[(size_t)n * HEADS + head];
    const float4 b = *reinterpret_cast<const float4*>(bias + c4);
    float v;
    float4 o;
    v = acc.x * iv + b.x; o.x = (v > 0.f) ? v : expm1f(v);
    v = acc.y * iv + b.y; o.y = (v > 0.f) ? v : expm1f(v);
    v = acc.z * iv + b.z; o.z = (v > 0.f) ? v : expm1f(v);
    v = acc.w * iv + b.w; o.w = (v > 0.f) ? v : expm1f(v);
    *reinterpret_cast<float4*>(out + (size_t)n * HU + c4) = o;
}

extern "C" void kernel_launch(void* const* d_in, const int* in_sizes, int n_in,
                              void* d_out, int out_size, void* d_ws, size_t ws_size,
                              hipStream_t stream) {
    const float* x = (const float*)d_in[0];
    const int* edges = (const int*)d_in[1];
    const float* W = (const float*)d_in[2];
    const float* ka1 = (const float*)d_in[3];
    // d_in[4] = ka2: unused by the reference
    const float* bias = (const float*)d_in[5];
    float* out = (float*)d_out;

    char* ws = (char*)d_ws;
    size_t off = 0;
    auto alloc = [&](size_t bytes) -> void* {
        void* p = ws + off;
        off = (off + bytes + 255) & ~size_t(255);
        return p;
    };
    __half* h = (__half*)alloc(sizeof(__half) * (size_t)N_NODES * HU);       // 25.6 MB
    __half* x16 = (__half*)alloc(sizeof(__half) * (size_t)N_NODES * D_FEAT); // 12.8 MB
    __half* Wt = (__half*)alloc(sizeof(__half) * D_FEAT * HU);               // 64 KB
    float* f = (float*)alloc(sizeof(float) * N_NODES * HEADS);               // 1.6 MB
    float* g = (float*)alloc(sizeof(float) * N_NODES * HEADS);               // 1.6 MB
    float* invd = (float*)alloc(sizeof(float) * N_NODES * HEADS);            // 1.6 MB
    int* counts = (int*)alloc(sizeof(int) * N_NODES);
    int* offs = (int*)alloc(sizeof(int) * N_NODES);
    int* partials = (int*)alloc(sizeof(int) * NBLK);
    int* elist = (int*)alloc(sizeof(int) * N_EDGES);                         // 3.2 MB
    __half* wlist = (__half*)alloc(sizeof(__half) * (size_t)N_EDGES * HEADS); // 12.8 MB

    hipMemsetAsync(counts, 0, sizeof(int) * N_NODES, stream);

    k_conv<<<XBLK + WBLK + EBLK, 256, 0, stream>>>(x, W, edges, x16, Wt, counts);
    k_gemm<<<N_NODES / 16, 64, 0, stream>>>(x16, Wt, ka1, h, f);
    k_scanA<<<NBLK, 256, 0, stream>>>(counts, partials);
    k_scanB<<<1, 256, 0, stream>>>(partials);
    k_scanC<<<NBLK, 256, 0, stream>>>(counts, partials, offs);
    k_fillg<<<(N_EDGES + 255) / 256, 256, 0, stream>>>(edges, f, g, offs, elist);
    k_max<<<(N_NODES + 3) / 4, 256, 0, stream>>>(elist, f, g, offs, counts, wlist, invd);
    k_out<<<(N_NODES + 3) / 4, 256, 0, stream>>>(h, elist, wlist, invd, offs, counts, bias, out);
}

// Round 7
// 218.484 us; speedup vs baseline: 1.1616x; 1.1616x over previous
//
#include <hip/hip_runtime.h>
#include <hip/hip_fp16.h>

#define N_NODES 50000
#define N_EDGES 800000
#define D_FEAT 128
#define HEADS 8
#define UNITS 32
#define HU (HEADS * UNITS) /* 256 */
#define LEAKY 0.2f
#define EPSV 1e-7f
#define NBLK 196 /* ceil(50000/256) */

typedef _Float16 half8 __attribute__((ext_vector_type(8)));
typedef float f32x4 __attribute__((ext_vector_type(4)));

struct h4pk { __half2 a, b; }; // 4 fp16 channels = 8 bytes

// ---- fused: x fp32->fp16 | W -> W^T fp16 | in-degree counts ----
#define XBLK 3125             /* 3125*256*8 = 6,400,000 = N_NODES*D_FEAT */
#define WBLK 128              /* 128*256 = 32768 = D_FEAT*HU */
#define EBLK 3125             /* 3125*256 = 800,000 = N_EDGES */
__global__ __launch_bounds__(256) void k_conv(const float* __restrict__ x,
                                              const float* __restrict__ W,
                                              const int* __restrict__ edges,
                                              __half* __restrict__ x16,
                                              __half* __restrict__ Wt,
                                              int* __restrict__ counts) {
    const int b = blockIdx.x, t = threadIdx.x;
    if (b < XBLK) {
        const int i = (b * 256 + t) * 8;
        const float4 v0 = *reinterpret_cast<const float4*>(x + i);
        const float4 v1 = *reinterpret_cast<const float4*>(x + i + 4);
        half8 o;
        o[0] = (_Float16)v0.x; o[1] = (_Float16)v0.y;
        o[2] = (_Float16)v0.z; o[3] = (_Float16)v0.w;
        o[4] = (_Float16)v1.x; o[5] = (_Float16)v1.y;
        o[6] = (_Float16)v1.z; o[7] = (_Float16)v1.w;
        *reinterpret_cast<half8*>(x16 + i) = o;
    } else if (b < XBLK + WBLK) {
        const int i = (b - XBLK) * 256 + t;   // i = n*128 + k
        const int n = i >> 7, k = i & 127;
        Wt[i] = __float2half(W[k * HU + n]);  // Wt[n][k] = W[k][n]
    } else {
        const int e = (b - XBLK - WBLK) * 256 + t;
        if (e < N_EDGES) atomicAdd(&counts[edges[2 * e + 1]], 1);
    }
}

// ---- MFMA GEMM: h(fp16) = x16 @ Wt^T, fused f = sum(h*ka1, units) ----
__global__ __launch_bounds__(64) void k_gemm(const __half* __restrict__ x16,
                                             const __half* __restrict__ Wt,
                                             const float* __restrict__ ka1,
                                             __half* __restrict__ h,
                                             float* __restrict__ f) {
    __shared__ __align__(16) __half hs[16 * HU]; // 8 KB
    const int l = threadIdx.x;
    const int row16 = l & 15, kg = l >> 4;
    const size_t rbase = (size_t)blockIdx.x * 16;

    half8 a[4];
#pragma unroll
    for (int ks = 0; ks < 4; ++ks)
        a[ks] = *reinterpret_cast<const half8*>(x16 + (rbase + row16) * D_FEAT + ks * 32 + kg * 8);

    f32x4 acc[16];
#pragma unroll
    for (int ct = 0; ct < 16; ++ct) acc[ct] = (f32x4){0.f, 0.f, 0.f, 0.f};

#pragma unroll
    for (int ct = 0; ct < 16; ++ct) {
        const __half* wp = Wt + (ct * 16 + row16) * D_FEAT + kg * 8;
#pragma unroll
        for (int ks = 0; ks < 4; ++ks) {
            const half8 bf = *reinterpret_cast<const half8*>(wp + ks * 32);
            acc[ct] = __builtin_amdgcn_mfma_f32_16x16x32_f16(a[ks], bf, acc[ct], 0, 0, 0);
        }
    }

#pragma unroll
    for (int ct = 0; ct < 16; ++ct) {
        const int col = ct * 16 + row16;
#pragma unroll
        for (int r = 0; r < 4; ++r)
            hs[(kg * 4 + r) * HU + col] = __float2half(acc[ct][r]);
    }
    __syncthreads();

#pragma unroll
    for (int j = 0; j < 8; ++j) {
        const int slot = j * 64 + l;
        const half8 v = *reinterpret_cast<const half8*>(hs + slot * 8);
        *reinterpret_cast<half8*>(h + rbase * HU + slot * 8) = v;
    }

#pragma unroll
    for (int hf = 0; hf < 2; ++hf) {
        const int o = hf * 64 + l;
        const int row = o >> 3, hd = o & 7;
        const __half* hp = hs + row * HU + hd * UNITS;
        const float* kp = ka1 + hd * UNITS;
        float s = 0.f;
#pragma unroll
        for (int u = 0; u < UNITS; u += 8) {
            const half8 hv = *reinterpret_cast<const half8*>(hp + u);
            const float4 k0 = *reinterpret_cast<const float4*>(kp + u);
            const float4 k1 = *reinterpret_cast<const float4*>(kp + u + 4);
            s += (float)hv[0] * k0.x + (float)hv[1] * k0.y + (float)hv[2] * k0.z + (float)hv[3] * k0.w;
            s += (float)hv[4] * k1.x + (float)hv[5] * k1.y + (float)hv[6] * k1.z + (float)hv[7] * k1.w;
        }
        f[rbase * HEADS + o] = s;
    }
}

// ---- hierarchical scan ----
__global__ __launch_bounds__(256) void k_scanA(const int* __restrict__ counts,
                                               int* __restrict__ partials) {
    const int i = blockIdx.x * 256 + threadIdx.x;
    int v = (i < N_NODES) ? counts[i] : 0;
#pragma unroll
    for (int m = 32; m >= 1; m >>= 1) v += __shfl_xor(v, m);
    __shared__ int ws[4];
    if ((threadIdx.x & 63) == 0) ws[threadIdx.x >> 6] = v;
    __syncthreads();
    if (threadIdx.x == 0) partials[blockIdx.x] = ws[0] + ws[1] + ws[2] + ws[3];
}

__global__ __launch_bounds__(256) void k_scanB(int* __restrict__ partials) {
    __shared__ int s[256];
    const int t = threadIdx.x;
    const int v = (t < NBLK) ? partials[t] : 0;
    s[t] = v;
    __syncthreads();
    for (int o = 1; o < 256; o <<= 1) {
        const int u = (t >= o) ? s[t - o] : 0;
        __syncthreads();
        s[t] += u;
        __syncthreads();
    }
    if (t < NBLK) partials[t] = s[t] - v; // exclusive
}

__global__ __launch_bounds__(256) void k_scanC(const int* __restrict__ counts,
                                               const int* __restrict__ partials,
                                               int* __restrict__ offs) {
    __shared__ int s[256];
    const int t = threadIdx.x;
    const int i = blockIdx.x * 256 + t;
    const int v = (i < N_NODES) ? counts[i] : 0;
    s[t] = v;
    __syncthreads();
    for (int o = 1; o < 256; o <<= 1) {
        const int u = (t >= o) ? s[t - o] : 0;
        __syncthreads();
        s[t] += u;
        __syncthreads();
    }
    if (i < N_NODES) offs[i] = partials[blockIdx.x] + s[t] - v; // exclusive
}

// ---- fused: g[v]=f[targets[v]] + CSR fill (offs becomes segment END) ----
__global__ __launch_bounds__(256) void k_fillg(const int* __restrict__ edges,
                                               const float* __restrict__ f,
                                               float* __restrict__ g,
                                               int* __restrict__ offs,
                                               int* __restrict__ elist) {
    const int i = blockIdx.x * 256 + threadIdx.x;
    if (i < N_NODES) {
        const int t2 = edges[2 * i + 1];
        const float4 A = *reinterpret_cast<const float4*>(f + (size_t)t2 * HEADS);
        const float4 B = *reinterpret_cast<const float4*>(f + (size_t)t2 * HEADS + 4);
        *reinterpret_cast<float4*>(g + (size_t)i * HEADS) = A;
        *reinterpret_cast<float4*>(g + (size_t)i * HEADS + 4) = B;
    }
    if (i < N_EDGES) {
        const int s = edges[2 * i];
        const int t = edges[2 * i + 1];
        const int p = atomicAdd(&offs[t], 1);
        elist[p] = s;
    }
}

// ---- single sweep, no-max softmax (safe: z <= ~8 << 88) + weighted gather ----
// w = exp(z) in fp32; d = sum w; out = (acc/d+eps) + bias, ELU.
__global__ __launch_bounds__(256) void k_out(const __half* __restrict__ h,
                                             const int* __restrict__ elist,
                                             const float* __restrict__ f,
                                             const float* __restrict__ g,
                                             const int* __restrict__ offs, // segment END
                                             const int* __restrict__ counts,
                                             const float* __restrict__ bias,
                                             float* __restrict__ out) {
    const int n = blockIdx.x * 4 + (threadIdx.x >> 6);
    if (n >= N_NODES) return;
    const int lane = threadIdx.x & 63;
    const int head = lane >> 3;
    const int c4 = lane * 4;
    const int end = offs[n];
    const int start = end - counts[n];
    const float fn = f[(size_t)n * HEADS + head];

    float d = 0.f;
    float4 acc = make_float4(0.f, 0.f, 0.f, 0.f);

    int p = start;
    // 4-edge unrolled steady state: batch loads -> 4+ gathers in flight
    for (; p + 4 <= end; p += 4) {
        const int s0 = elist[p + 0];
        const int s1 = elist[p + 1];
        const int s2 = elist[p + 2];
        const int s3 = elist[p + 3];
        const float gz0 = g[(size_t)s0 * HEADS + head];
        const float gz1 = g[(size_t)s1 * HEADS + head];
        const float gz2 = g[(size_t)s2 * HEADS + head];
        const float gz3 = g[(size_t)s3 * HEADS + head];
        const h4pk hv0 = *reinterpret_cast<const h4pk*>(h + (size_t)s0 * HU + c4);
        const h4pk hv1 = *reinterpret_cast<const h4pk*>(h + (size_t)s1 * HU + c4);
        const h4pk hv2 = *reinterpret_cast<const h4pk*>(h + (size_t)s2 * HU + c4);
        const h4pk hv3 = *reinterpret_cast<const h4pk*>(h + (size_t)s3 * HU + c4);

        float z0 = fn + gz0; z0 = (z0 > 0.f) ? z0 : LEAKY * z0;
        float z1 = fn + gz1; z1 = (z1 > 0.f) ? z1 : LEAKY * z1;
        float z2 = fn + gz2; z2 = (z2 > 0.f) ? z2 : LEAKY * z2;
        float z3 = fn + gz3; z3 = (z3 > 0.f) ? z3 : LEAKY * z3;
        const float w0 = __expf(z0);
        const float w1 = __expf(z1);
        const float w2 = __expf(z2);
        const float w3 = __expf(z3);
        d += (w0 + w1) + (w2 + w3);

        float2 fa, fb;
        fa = __half22float2(hv0.a); fb = __half22float2(hv0.b);
        acc.x += w0 * fa.x; acc.y += w0 * fa.y; acc.z += w0 * fb.x; acc.w += w0 * fb.y;
        fa = __half22float2(hv1.a); fb = __half22float2(hv1.b);
        acc.x += w1 * fa.x; acc.y += w1 * fa.y; acc.z += w1 * fb.x; acc.w += w1 * fb.y;
        fa = __half22float2(hv2.a); fb = __half22float2(hv2.b);
        acc.x += w2 * fa.x; acc.y += w2 * fa.y; acc.z += w2 * fb.x; acc.w += w2 * fb.y;
        fa = __half22float2(hv3.a); fb = __half22float2(hv3.b);
        acc.x += w3 * fa.x; acc.y += w3 * fa.y; acc.z += w3 * fb.x; acc.w += w3 * fb.y;
    }
    for (; p < end; ++p) {
        const int s = elist[p];
        float z = fn + g[(size_t)s * HEADS + head];
        z = (z > 0.f) ? z : LEAKY * z;
        const float w = __expf(z);
        const h4pk hv = *reinterpret_cast<const h4pk*>(h + (size_t)s * HU + c4);
        const float2 fa = __half22float2(hv.a);
        const float2 fb = __half22float2(hv.b);
        d += w;
        acc.x += w * fa.x;
        acc.y += w * fa.y;
        acc.z += w * fb.x;
        acc.w += w * fb.y;
    }

    const float inv = 1.f / (d + EPSV);
    const float4 b = *reinterpret_cast<const float4*>(bias + c4);
    float v;
    float4 o;
    v = acc.x * inv + b.x; o.x = (v > 0.f) ? v : expm1f(v);
    v = acc.y * inv + b.y; o.y = (v > 0.f) ? v : expm1f(v);
    v = acc.z * inv + b.z; o.z = (v > 0.f) ? v : expm1f(v);
    v = acc.w * inv + b.w; o.w = (v > 0.f) ? v : expm1f(v);
    *reinterpret_cast<float4*>(out + (size_t)n * HU + c4) = o;
}

extern "C" void kernel_launch(void* const* d_in, const int* in_sizes, int n_in,
                              void* d_out, int out_size, void* d_ws, size_t ws_size,
                              hipStream_t stream) {
    const float* x = (const float*)d_in[0];
    const int* edges = (const int*)d_in[1];
    const float* W = (const float*)d_in[2];
    const float* ka1 = (const float*)d_in[3];
    // d_in[4] = ka2: unused by the reference
    const float* bias = (const float*)d_in[5];
    float* out = (float*)d_out;

    char* ws = (char*)d_ws;
    size_t off = 0;
    auto alloc = [&](size_t bytes) -> void* {
        void* p = ws + off;
        off = (off + bytes + 255) & ~size_t(255);
        return p;
    };
    __half* h = (__half*)alloc(sizeof(__half) * (size_t)N_NODES * HU);       // 25.6 MB
    __half* x16 = (__half*)alloc(sizeof(__half) * (size_t)N_NODES * D_FEAT); // 12.8 MB
    __half* Wt = (__half*)alloc(sizeof(__half) * D_FEAT * HU);               // 64 KB
    float* f = (float*)alloc(sizeof(float) * N_NODES * HEADS);               // 1.6 MB
    float* g = (float*)alloc(sizeof(float) * N_NODES * HEADS);               // 1.6 MB
    int* counts = (int*)alloc(sizeof(int) * N_NODES);
    int* offs = (int*)alloc(sizeof(int) * N_NODES);
    int* partials = (int*)alloc(sizeof(int) * NBLK);
    int* elist = (int*)alloc(sizeof(int) * N_EDGES);                         // 3.2 MB

    hipMemsetAsync(counts, 0, sizeof(int) * N_NODES, stream);

    k_conv<<<XBLK + WBLK + EBLK, 256, 0, stream>>>(x, W, edges, x16, Wt, counts);
    k_gemm<<<N_NODES / 16, 64, 0, stream>>>(x16, Wt, ka1, h, f);
    k_scanA<<<NBLK, 256, 0, stream>>>(counts, partials);
    k_scanB<<<1, 256, 0, stream>>>(partials);
    k_scanC<<<NBLK, 256, 0, stream>>>(counts, partials, offs);
    k_fillg<<<(N_EDGES + 255) / 256, 256, 0, stream>>>(edges, f, g, offs, elist);
    k_out<<<(N_NODES + 3) / 4, 256, 0, stream>>>(h, elist, f, g, offs, counts, bias, out);
}